// Round 9
// baseline (521.558 us; speedup 1.0000x reference)
//
#include <hip/hip_runtime.h>
#include <math.h>

#define L 2048
#define BSZ 2
#define NH 16
#define DH 64
#define DM 1024
#define GK 1024
#define SCALE_F 0.125f

// partial-accumulator slot: 64x64 O (f32) + 64 l values
#define PSLOT 4160

typedef __attribute__((ext_vector_type(8))) __bf16 bf16x8;
typedef __attribute__((ext_vector_type(4))) __bf16 bf16x4;
typedef __attribute__((ext_vector_type(4))) float f32x4;

// ---------------------------------------------------------------------------
// cast fp32 -> bf16 for two tensors in one launch
// ---------------------------------------------------------------------------
__global__ __launch_bounds__(256)
void cast2_f32_bf16(const float* __restrict__ a, int na4,
                    const float* __restrict__ b, int nb4,
                    __bf16* __restrict__ da, __bf16* __restrict__ db_)
{
    int i = blockIdx.x * 256 + threadIdx.x;
    int stride = gridDim.x * 256;
    int tot = na4 + nb4;
    for (; i < tot; i += stride) {
        const float4* s; bf16x4* d; int idx;
        if (i < na4) { s = (const float4*)a; d = (bf16x4*)da; idx = i; }
        else         { s = (const float4*)b; d = (bf16x4*)db_; idx = i - na4; }
        float4 v = s[idx];
        bf16x4 o = { (__bf16)v.x, (__bf16)v.y, (__bf16)v.z, (__bf16)v.w };
        d[idx] = o;
    }
}

// ---------------------------------------------------------------------------
// Transpose 5x [1024x1024] fp32 -> bf16 transposed
// ---------------------------------------------------------------------------
__global__ __launch_bounds__(256)
void transpose_w5(const float* s0, const float* s1, const float* s2,
                  const float* s3, const float* s4,
                  __bf16* d0, __bf16* d1, __bf16* d2, __bf16* d3, __bf16* d4)
{
    const float* srcs[5] = { s0, s1, s2, s3, s4 };
    __bf16*      dsts[5] = { d0, d1, d2, d3, d4 };
    const float* src = srcs[blockIdx.z];
    __bf16*      dst = dsts[blockIdx.z];
    __shared__ float tile[32][33];
    const int tx = threadIdx.x & 31, ty = threadIdx.x >> 5;
    const int x0 = blockIdx.x * 32, y0 = blockIdx.y * 32;
    #pragma unroll
    for (int i = 0; i < 32; i += 8)
        tile[ty + i][tx] = src[(size_t)(y0 + ty + i) * 1024 + x0 + tx];
    __syncthreads();
    #pragma unroll
    for (int i = 0; i < 32; i += 8)
        dst[(size_t)(x0 + ty + i) * 1024 + y0 + tx] = (__bf16)tile[tx][ty + i];
}

// ---------------------------------------------------------------------------
// Per-head V transpose: v[bh][j][d] -> vT[bh][d][j]  (bf16)
// grid: x = L/32, y = DH/32, z = bh
// ---------------------------------------------------------------------------
__global__ __launch_bounds__(256)
void transpose_v(const __bf16* __restrict__ src, __bf16* __restrict__ dst)
{
    __shared__ __bf16 tile[32][34];
    const __bf16* s = src + (size_t)blockIdx.z * L * DH;
    __bf16*       d = dst + (size_t)blockIdx.z * L * DH;
    const int tx = threadIdx.x & 31, ty = threadIdx.x >> 5;
    const int j0 = blockIdx.x * 32, d0 = blockIdx.y * 32;
    #pragma unroll
    for (int i = 0; i < 32; i += 8)
        tile[ty + i][tx] = s[(size_t)(j0 + ty + i) * DH + d0 + tx];
    __syncthreads();
    #pragma unroll
    for (int i = 0; i < 32; i += 8)
        d[(size_t)(d0 + ty + i) * L + j0 + tx] = tile[tx][ty + i];
}

// ---------------------------------------------------------------------------
// bf16 MFMA GEMM, m97 structure. sched 0: flattened QKV(768 blocks)+RK(128,
// writes o4 with bias b3). sched 1: O-projection (2D grid), fp32 out.
// ---------------------------------------------------------------------------
__global__ __launch_bounds__(256)
void gemm_bf16(const __bf16* __restrict__ A0, const __bf16* __restrict__ A1,
               const __bf16* __restrict__ B0, const __bf16* __restrict__ B1,
               int sched,
               __bf16* __restrict__ o0, __bf16* __restrict__ o1,
               __bf16* __restrict__ o2, __bf16* __restrict__ o3,
               __bf16* __restrict__ o4,
               const float* __restrict__ b0, const float* __restrict__ b1,
               const float* __restrict__ b2, const float* __restrict__ b3,
               const float* __restrict__ rwbf, const float* __restrict__ rrbf,
               float* __restrict__ of)
{
    __shared__ __bf16 As[128 * 64];
    __shared__ __bf16 Bs[128 * 64];

    const __bf16 *A, *Bt;
    int mode, bm, bn;
    if (sched == 0) {
        int id = blockIdx.x;
        if (id < 768) { A = A0; Bt = B0; mode = 0; bm = (id & 31) * 128; bn = (id >> 5) * 128; }
        else { id -= 768; A = A1; Bt = B1; mode = 1; bm = (id & 15) * 128; bn = (id >> 4) * 128; }
    } else {
        A = A0; Bt = B0; mode = 2; bm = blockIdx.x * 128; bn = blockIdx.y * 128;
    }

    const int t    = threadIdx.x;
    const int w    = t >> 6;
    const int lane = t & 63;
    const int row16 = lane & 15;
    const int kgrp  = lane >> 4;
    const int wr = w >> 1, wc = w & 1;

    f32x4 acc[4][4];
    #pragma unroll
    for (int mi = 0; mi < 4; ++mi)
        #pragma unroll
        for (int ni = 0; ni < 4; ++ni)
            acc[mi][ni] = (f32x4){0.f, 0.f, 0.f, 0.f};

    for (int k0 = 0; k0 < GK; k0 += 64) {
        __syncthreads();
        #pragma unroll
        for (int it = 0; it < 4; ++it) {
            const int lin = (it * 256 + t) * 16;
            const int row = lin >> 7;
            const int kb  = lin & 127;
            const char* ga = (const char*)(A + (size_t)(bm + row) * GK + k0) + kb;
            __builtin_amdgcn_global_load_lds(
                (const __attribute__((address_space(1))) void*)ga,
                (__attribute__((address_space(3))) void*)((char*)As + lin), 16, 0, 0);
            const char* gb = (const char*)(Bt + (size_t)(bn + row) * GK + k0) + kb;
            __builtin_amdgcn_global_load_lds(
                (const __attribute__((address_space(1))) void*)gb,
                (__attribute__((address_space(3))) void*)((char*)Bs + lin), 16, 0, 0);
        }
        __syncthreads();

        #pragma unroll
        for (int ks = 0; ks < 2; ++ks) {
            bf16x8 af[4], bfr[4];
            #pragma unroll
            for (int mi = 0; mi < 4; ++mi)
                af[mi] = *reinterpret_cast<const bf16x8*>(
                    &As[(wr * 64 + mi * 16 + row16) * 64 + kgrp * 8 + ks * 32]);
            #pragma unroll
            for (int ni = 0; ni < 4; ++ni)
                bfr[ni] = *reinterpret_cast<const bf16x8*>(
                    &Bs[(wc * 64 + ni * 16 + row16) * 64 + kgrp * 8 + ks * 32]);
            #pragma unroll
            for (int mi = 0; mi < 4; ++mi)
                #pragma unroll
                for (int ni = 0; ni < 4; ++ni)
                    acc[mi][ni] = __builtin_amdgcn_mfma_f32_16x16x32_bf16(
                        af[mi], bfr[ni], acc[mi][ni], 0, 0, 0);
        }
    }

    #pragma unroll
    for (int mi = 0; mi < 4; ++mi) {
        #pragma unroll
        for (int ni = 0; ni < 4; ++ni) {
            #pragma unroll
            for (int r = 0; r < 4; ++r) {
                const int row = bm + wr * 64 + mi * 16 + kgrp * 4 + r;
                const int col = bn + wc * 64 + ni * 16 + row16;
                const float val = acc[mi][ni][r];
                if (mode == 0) {
                    const int which = col >> 10, c = col & 1023;
                    const int n = c >> 6, dh = c & 63;
                    const int i = row >> 1, b = row & 1;
                    const size_t idx = (((size_t)(b * NH + n) * L) + i) * DH + dh;
                    if (which == 0) {
                        const float v0 = val + b0[c];
                        o0[idx] = (__bf16)(v0 + rwbf[c]);
                        o1[idx] = (__bf16)(v0 + rrbf[c]);
                    } else if (which == 1) {
                        o2[idx] = (__bf16)(val + b1[c]);
                    } else {
                        o3[idx] = (__bf16)(val + b2[c]);
                    }
                } else if (mode == 1) {
                    const int n = col >> 6, dh = col & 63;
                    o4[((size_t)n * L + row) * DH + dh] = (__bf16)(val + b3[col]);
                } else {
                    of[(size_t)row * DM + col] = val + b0[col];
                }
            }
        }
    }
}

// ---------------------------------------------------------------------------
// Flash-decoding attention partials, BARRIER-FREE: all operands direct from
// global (L2-resident); only per-wave-private pt LDS remains. Fixed m=0
// softmax -> partials combine by pure addition (atomicAdd into P).
// ---------------------------------------------------------------------------
__global__ __launch_bounds__(256, 4)
void attn_partial(const __bf16* __restrict__ qwg, const __bf16* __restrict__ qrg,
                  const __bf16* __restrict__ kg,  const __bf16* __restrict__ vTg,
                  const __bf16* __restrict__ rkg, float* __restrict__ P)
{
    __shared__ __bf16 pt [4][16][72];  // per-wave P tile (wave-private)

    // decode chunk id
    int x = blockIdx.x;
    int it, jc;
    if (x < 8)       { it = x;                      jc = 0; }
    else if (x < 24) { int y = x - 8;  it = 8  + (y >> 1); jc = y & 1; }
    else if (x < 48) { int y = x - 24; it = 16 + y / 3;    jc = y - (y / 3) * 3; }
    else             { int y = x - 48; it = 24 + (y >> 2); jc = y & 3; }

    const int t    = threadIdx.x;
    const int w    = t >> 6;
    const int lane = t & 63;
    const int row16 = lane & 15;
    const int kgrp  = lane >> 4;

    const int bh = blockIdx.y;
    const int n  = bh & (NH - 1);
    const int i0 = it * 64;
    const int i0w = i0 + w * 16;
    const int jstart = jc * 512;
    const int jend   = min(jstart + 512, i0 + 64);   // exclusive

    const __bf16* qwb = qwg + (size_t)bh * L * DH;
    const __bf16* qrb = qrg + (size_t)bh * L * DH;
    const __bf16* kb  = kg  + (size_t)bh * L * DH;
    const __bf16* vTb = vTg + (size_t)bh * L * DH;   // [d][j] layout
    const __bf16* rkb = rkg + (size_t)n  * L * DH;

    bf16x8 qwf[2], qrf[2];
    #pragma unroll
    for (int ks = 0; ks < 2; ++ks) {
        size_t off = (size_t)(i0w + row16) * DH + kgrp * 8 + ks * 32;
        qwf[ks] = *reinterpret_cast<const bf16x8*>(qwb + off);
        qrf[ks] = *reinterpret_cast<const bf16x8*>(qrb + off);
    }

    float l_run[4] = {0.f, 0.f, 0.f, 0.f};
    f32x4 O[4];
    #pragma unroll
    for (int cb = 0; cb < 4; ++cb) O[cb] = (f32x4){0.f, 0.f, 0.f, 0.f};

    for (int j0 = jstart; j0 < jend; j0 += 64) {
        // ---- AC = QW · K^T  (K direct from global) ----
        f32x4 ac[4];
        #pragma unroll
        for (int cb = 0; cb < 4; ++cb) ac[cb] = (f32x4){0.f, 0.f, 0.f, 0.f};
        #pragma unroll
        for (int ks = 0; ks < 2; ++ks)
            #pragma unroll
            for (int cb = 0; cb < 4; ++cb) {
                bf16x8 kf = *reinterpret_cast<const bf16x8*>(
                    kb + (size_t)(j0 + 16 * cb + row16) * DH + kgrp * 8 + ks * 32);
                ac[cb] = __builtin_amdgcn_mfma_f32_16x16x32_bf16(qwf[ks], kf, ac[cb], 0, 0, 0);
            }

        // ---- Dband = QR · RK_band^T (rk direct from global) ----
        f32x4 db[5];
        #pragma unroll
        for (int cb = 0; cb < 5; ++cb) db[cb] = (f32x4){0.f, 0.f, 0.f, 0.f};
        const int pw0 = (L - 1) + j0 - (i0w + 15);
        #pragma unroll
        for (int ks = 0; ks < 2; ++ks)
            #pragma unroll
            for (int cb = 0; cb < 5; ++cb) {
                int p = pw0 + 16 * cb + row16;
                p = p > (L - 1) ? (L - 1) : p;     // clamped rows feed masked cols only
                bf16x8 rf = *reinterpret_cast<const bf16x8*>(
                    rkb + (size_t)p * DH + kgrp * 8 + ks * 32);
                db[cb] = __builtin_amdgcn_mfma_f32_16x16x32_bf16(qrf[ks], rf, db[cb], 0, 0, 0);
            }

        // ---- softmax (fixed m=0) with in-register shift ----
        #pragma unroll
        for (int r = 0; r < 4; ++r) {
            const int ri = kgrp * 4 + r;
            const int i_glob = i0w + ri;
            const int u  = row16 + 15 - ri;        // 0..30
            const int lo = u & 15;
            const int hi = u >> 4;
            const int srclane = (lane & 48) | lo;
            float T[5];
            #pragma unroll
            for (int c2 = 0; c2 < 5; ++c2)
                T[c2] = __shfl(db[c2][r], srclane, 64);
            float rsum = 0.f;
            #pragma unroll
            for (int cb = 0; cb < 4; ++cb) {
                const int jj = 16 * cb + row16;
                float bd = hi ? T[cb + 1] : T[cb];
                float s = SCALE_F * (ac[cb][r] + bd);
                if (j0 + jj > i_glob) s = -INFINITY;
                float p = __expf(s);
                pt[w][ri][jj] = (__bf16)p;
                rsum += p;
            }
            #pragma unroll
            for (int off = 1; off < 16; off <<= 1)
                rsum += __shfl_xor(rsum, off);
            l_run[r] += rsum;
        }

        // ---- O += P · V  (A=P from wave-private pt, B=V^T direct global) ----
        #pragma unroll
        for (int ks = 0; ks < 2; ++ks) {
            bf16x8 pf = *reinterpret_cast<const bf16x8*>(&pt[w][row16][kgrp * 8 + ks * 32]);
            #pragma unroll
            for (int cb = 0; cb < 4; ++cb) {
                bf16x8 vf = *reinterpret_cast<const bf16x8*>(
                    vTb + (size_t)(16 * cb + row16) * L + j0 + kgrp * 8 + ks * 32);
                O[cb] = __builtin_amdgcn_mfma_f32_16x16x32_bf16(pf, vf, O[cb], 0, 0, 0);
            }
        }
    }

    // ---- accumulate partials: O rows into P[bh][it][row*64+col], l into +4096 ----
    float* Pb = P + ((size_t)bh * 32 + it) * PSLOT;
    #pragma unroll
    for (int r = 0; r < 4; ++r) {
        const int row = w * 16 + kgrp * 4 + r;
        #pragma unroll
        for (int cb = 0; cb < 4; ++cb)
            atomicAdd(&Pb[row * 64 + 16 * cb + row16], O[cb][r]);
        if (row16 == 0)
            atomicAdd(&Pb[4096 + row], l_run[r]);
    }
}

// ---------------------------------------------------------------------------
// Combine partials: av = O_sum / l_sum, bf16, attn_vec layout.
// ---------------------------------------------------------------------------
__global__ __launch_bounds__(256)
void attn_reduce(const float* __restrict__ P, __bf16* __restrict__ av)
{
    const int bh = blockIdx.y;
    const int it = blockIdx.x;
    const int n = bh & (NH - 1), b = bh >> 4;
    const float* Pb = P + ((size_t)bh * 32 + it) * PSLOT;
    const int t = threadIdx.x;
    const int row = t >> 2;
    const int c0 = (t & 3) * 16;
    const float inv = 1.0f / Pb[4096 + row];
    const int i_glob = it * 64 + row;
    __bf16* dst = av + (size_t)(i_glob * BSZ + b) * (NH * DH) + n * DH + c0;
    #pragma unroll
    for (int v4 = 0; v4 < 4; ++v4) {
        float4 o = *reinterpret_cast<const float4*>(&Pb[row * 64 + c0 + v4 * 4]);
        bf16x4 ov = { (__bf16)(o.x * inv), (__bf16)(o.y * inv),
                      (__bf16)(o.z * inv), (__bf16)(o.w * inv) };
        *reinterpret_cast<bf16x4*>(dst + v4 * 4) = ov;
    }
}

// ---------------------------------------------------------------------------
// Fused residual + LayerNorm
// ---------------------------------------------------------------------------
__global__ __launch_bounds__(256)
void ln_fused(const float* __restrict__ w, const float* __restrict__ ao,
              const float* __restrict__ g, const float* __restrict__ bb,
              float* __restrict__ out)
{
    const int row = blockIdx.x;
    const float* wr = w  + (size_t)row * DM;
    const float* ar = ao + (size_t)row * DM;
    const int t = threadIdx.x;
    float x[4];
    float s = 0.f;
    #pragma unroll
    for (int j = 0; j < 4; ++j) {
        int c = t + j * 256;
        x[j] = wr[c] + ar[c];
        s += x[j];
    }
    __shared__ float red[4];
    #pragma unroll
    for (int off = 1; off < 64; off <<= 1) s += __shfl_xor(s, off);
    int wid = t >> 6, lane = t & 63;
    if (lane == 0) red[wid] = s;
    __syncthreads();
    float mu = (red[0] + red[1] + red[2] + red[3]) * (1.0f / DM);
    float ss = 0.f;
    #pragma unroll
    for (int j = 0; j < 4; ++j) { float d = x[j] - mu; ss += d * d; }
    #pragma unroll
    for (int off = 1; off < 64; off <<= 1) ss += __shfl_xor(ss, off);
    __syncthreads();
    if (lane == 0) red[wid] = ss;
    __syncthreads();
    float var = (red[0] + red[1] + red[2] + red[3]) * (1.0f / DM);
    float rstd = rsqrtf(var + 1e-5f);
    #pragma unroll
    for (int j = 0; j < 4; ++j) {
        int c = t + j * 256;
        out[(size_t)row * DM + c] = (x[j] - mu) * rstd * g[c] + bb[c];
    }
}

extern "C" void kernel_launch(void* const* d_in, const int* in_sizes, int n_in,
                              void* d_out, int out_size, void* d_ws, size_t ws_size,
                              hipStream_t stream)
{
    (void)in_sizes; (void)n_in; (void)out_size; (void)ws_size;
    const float* w   = (const float*)d_in[0];
    const float* r   = (const float*)d_in[1];
    const float* rwb = (const float*)d_in[2];
    const float* rrb = (const float*)d_in[3];
    const float* Wq  = (const float*)d_in[4];
    const float* bq  = (const float*)d_in[5];
    const float* Wk  = (const float*)d_in[6];
    const float* bk  = (const float*)d_in[7];
    const float* Wv  = (const float*)d_in[8];
    const float* bv  = (const float*)d_in[9];
    const float* Wr  = (const float*)d_in[10];
    const float* br  = (const float*)d_in[11];
    const float* Wo  = (const float*)d_in[12];
    const float* bo  = (const float*)d_in[13];
    const float* lng = (const float*)d_in[14];
    const float* lnb = (const float*)d_in[15];
    float* out = (float*)d_out;

    const size_t NQ = (size_t)BSZ * NH * L * DH;   // 4.19M
    const size_t PN = (size_t)BSZ * NH * 32 * PSLOT;  // 4.26M f32 partial buffer
    char* wsb = (char*)d_ws;
    __bf16* w_bf    = (__bf16*)wsb;  wsb += (size_t)2 * L * DM * 2;
    __bf16* r_bf    = (__bf16*)wsb;  wsb += (size_t)L * DM * 2;
    __bf16* wqkv_t  = (__bf16*)wsb;  wsb += (size_t)3 * DM * DM * 2;
    __bf16* wr_t    = (__bf16*)wsb;  wsb += (size_t)DM * DM * 2;
    __bf16* wo_t    = (__bf16*)wsb;  wsb += (size_t)DM * DM * 2;
    __bf16* qw_ws   = (__bf16*)wsb;  wsb += NQ * 2;
    __bf16* qr_ws   = (__bf16*)wsb;  wsb += NQ * 2;
    __bf16* k_ws    = (__bf16*)wsb;  wsb += NQ * 2;
    __bf16* v_ws    = (__bf16*)wsb;  wsb += NQ * 2;
    __bf16* vT_ws   = (__bf16*)wsb;  wsb += NQ * 2;
    __bf16* rk_ws   = (__bf16*)wsb;  wsb += (size_t)NH * L * DH * 2;
    __bf16* av_ws   = (__bf16*)wsb;  wsb += NQ * 2;
    float*  P_ws    = (float*)wsb;   // PN floats; ao_ws ALIASES this region:
    float*  ao_ws   = P_ws;          // P consumed by attn_reduce before o-proj writes ao

    dim3 blk(256);
    // zero partial accumulators (capture-legal async memset)
    hipMemsetAsync(P_ws, 0, PN * sizeof(float), stream);

    cast2_f32_bf16<<<dim3(1536), blk, 0, stream>>>(
        w, (2 * L * DM) / 4, r, (L * DM) / 4, w_bf, r_bf);
    transpose_w5<<<dim3(32, 32, 5), blk, 0, stream>>>(
        Wq, Wk, Wv, Wr, Wo,
        wqkv_t, wqkv_t + (size_t)DM * DM, wqkv_t + (size_t)2 * DM * DM, wr_t, wo_t);

    // fused QKV (768 blocks) + RK (128 blocks -> o4/b3)
    gemm_bf16<<<dim3(896), blk, 0, stream>>>(w_bf, r_bf, wqkv_t, wr_t, 0,
        qw_ws, qr_ws, k_ws, v_ws, rk_ws, bq, bk, bv, br, rwb, rrb, nullptr);

    // V transpose for direct-global PV B-operand
    transpose_v<<<dim3(L / 32, DH / 32, BSZ * NH), blk, 0, stream>>>(v_ws, vT_ws);

    // flash-decoding attention: barrier-free partials + reduce
    attn_partial<<<dim3(80, BSZ * NH), blk, 0, stream>>>(
        qw_ws, qr_ws, k_ws, vT_ws, rk_ws, P_ws);
    attn_reduce<<<dim3(32, BSZ * NH), blk, 0, stream>>>(P_ws, av_ws);

    // output projection -> fp32 (overwrites P region, already consumed)
    gemm_bf16<<<dim3(32, 8), blk, 0, stream>>>(av_ws, nullptr, wo_t, nullptr, 1,
        nullptr, nullptr, nullptr, nullptr, nullptr, bo, nullptr, nullptr, nullptr,
        nullptr, nullptr, ao_ws);

    ln_fused<<<dim3(L * BSZ), blk, 0, stream>>>(w, ao_ws, lng, lnb, out);
}

// Round 10
// 407.424 us; speedup vs baseline: 1.2801x; 1.2801x over previous
//
#include <hip/hip_runtime.h>
#include <math.h>

#define L 2048
#define BSZ 2
#define NH 16
#define DH 64
#define DM 1024
#define GK 1024
#define SCALE_F 0.125f

// partial-accumulator slot: 64x64 O (f32) + 64 l values
#define PSLOT 4160

typedef __attribute__((ext_vector_type(8))) __bf16 bf16x8;
typedef __attribute__((ext_vector_type(4))) __bf16 bf16x4;
typedef __attribute__((ext_vector_type(4))) float f32x4;

// ---------------------------------------------------------------------------
// cast fp32 -> bf16 for two tensors in one launch
// ---------------------------------------------------------------------------
__global__ __launch_bounds__(256)
void cast2_f32_bf16(const float* __restrict__ a, int na4,
                    const float* __restrict__ b, int nb4,
                    __bf16* __restrict__ da, __bf16* __restrict__ db_)
{
    int i = blockIdx.x * 256 + threadIdx.x;
    int stride = gridDim.x * 256;
    int tot = na4 + nb4;
    for (; i < tot; i += stride) {
        const float4* s; bf16x4* d; int idx;
        if (i < na4) { s = (const float4*)a; d = (bf16x4*)da; idx = i; }
        else         { s = (const float4*)b; d = (bf16x4*)db_; idx = i - na4; }
        float4 v = s[idx];
        bf16x4 o = { (__bf16)v.x, (__bf16)v.y, (__bf16)v.z, (__bf16)v.w };
        d[idx] = o;
    }
}

// ---------------------------------------------------------------------------
// Transpose 5x [1024x1024] fp32 -> bf16 transposed
// ---------------------------------------------------------------------------
__global__ __launch_bounds__(256)
void transpose_w5(const float* s0, const float* s1, const float* s2,
                  const float* s3, const float* s4,
                  __bf16* d0, __bf16* d1, __bf16* d2, __bf16* d3, __bf16* d4)
{
    const float* srcs[5] = { s0, s1, s2, s3, s4 };
    __bf16*      dsts[5] = { d0, d1, d2, d3, d4 };
    const float* src = srcs[blockIdx.z];
    __bf16*      dst = dsts[blockIdx.z];
    __shared__ float tile[32][33];
    const int tx = threadIdx.x & 31, ty = threadIdx.x >> 5;
    const int x0 = blockIdx.x * 32, y0 = blockIdx.y * 32;
    #pragma unroll
    for (int i = 0; i < 32; i += 8)
        tile[ty + i][tx] = src[(size_t)(y0 + ty + i) * 1024 + x0 + tx];
    __syncthreads();
    #pragma unroll
    for (int i = 0; i < 32; i += 8)
        dst[(size_t)(x0 + ty + i) * 1024 + y0 + tx] = (__bf16)tile[tx][ty + i];
}

// ---------------------------------------------------------------------------
// Per-head V transpose: v[bh][j][d] -> vT[bh][d][j]  (bf16)
// ---------------------------------------------------------------------------
__global__ __launch_bounds__(256)
void transpose_v(const __bf16* __restrict__ src, __bf16* __restrict__ dst)
{
    __shared__ __bf16 tile[32][34];
    const __bf16* s = src + (size_t)blockIdx.z * L * DH;
    __bf16*       d = dst + (size_t)blockIdx.z * L * DH;
    const int tx = threadIdx.x & 31, ty = threadIdx.x >> 5;
    const int j0 = blockIdx.x * 32, d0 = blockIdx.y * 32;
    #pragma unroll
    for (int i = 0; i < 32; i += 8)
        tile[ty + i][tx] = s[(size_t)(j0 + ty + i) * DH + d0 + tx];
    __syncthreads();
    #pragma unroll
    for (int i = 0; i < 32; i += 8)
        d[(size_t)(d0 + ty + i) * L + j0 + tx] = tile[tx][ty + i];
}

// ---------------------------------------------------------------------------
// bf16 MFMA GEMM, m97 structure. sched 0: flattened QKV(768 blocks)+RK(128,
// writes o4 with bias b3). sched 1: O-projection (2D grid), fp32 out.
// ---------------------------------------------------------------------------
__global__ __launch_bounds__(256)
void gemm_bf16(const __bf16* __restrict__ A0, const __bf16* __restrict__ A1,
               const __bf16* __restrict__ B0, const __bf16* __restrict__ B1,
               int sched,
               __bf16* __restrict__ o0, __bf16* __restrict__ o1,
               __bf16* __restrict__ o2, __bf16* __restrict__ o3,
               __bf16* __restrict__ o4,
               const float* __restrict__ b0, const float* __restrict__ b1,
               const float* __restrict__ b2, const float* __restrict__ b3,
               const float* __restrict__ rwbf, const float* __restrict__ rrbf,
               float* __restrict__ of)
{
    __shared__ __bf16 As[128 * 64];
    __shared__ __bf16 Bs[128 * 64];

    const __bf16 *A, *Bt;
    int mode, bm, bn;
    if (sched == 0) {
        int id = blockIdx.x;
        if (id < 768) { A = A0; Bt = B0; mode = 0; bm = (id & 31) * 128; bn = (id >> 5) * 128; }
        else { id -= 768; A = A1; Bt = B1; mode = 1; bm = (id & 15) * 128; bn = (id >> 4) * 128; }
    } else {
        A = A0; Bt = B0; mode = 2; bm = blockIdx.x * 128; bn = blockIdx.y * 128;
    }

    const int t    = threadIdx.x;
    const int w    = t >> 6;
    const int lane = t & 63;
    const int row16 = lane & 15;
    const int kgrp  = lane >> 4;
    const int wr = w >> 1, wc = w & 1;

    f32x4 acc[4][4];
    #pragma unroll
    for (int mi = 0; mi < 4; ++mi)
        #pragma unroll
        for (int ni = 0; ni < 4; ++ni)
            acc[mi][ni] = (f32x4){0.f, 0.f, 0.f, 0.f};

    for (int k0 = 0; k0 < GK; k0 += 64) {
        __syncthreads();
        #pragma unroll
        for (int it = 0; it < 4; ++it) {
            const int lin = (it * 256 + t) * 16;
            const int row = lin >> 7;
            const int kb  = lin & 127;
            const char* ga = (const char*)(A + (size_t)(bm + row) * GK + k0) + kb;
            __builtin_amdgcn_global_load_lds(
                (const __attribute__((address_space(1))) void*)ga,
                (__attribute__((address_space(3))) void*)((char*)As + lin), 16, 0, 0);
            const char* gb = (const char*)(Bt + (size_t)(bn + row) * GK + k0) + kb;
            __builtin_amdgcn_global_load_lds(
                (const __attribute__((address_space(1))) void*)gb,
                (__attribute__((address_space(3))) void*)((char*)Bs + lin), 16, 0, 0);
        }
        __syncthreads();

        #pragma unroll
        for (int ks = 0; ks < 2; ++ks) {
            bf16x8 af[4], bfr[4];
            #pragma unroll
            for (int mi = 0; mi < 4; ++mi)
                af[mi] = *reinterpret_cast<const bf16x8*>(
                    &As[(wr * 64 + mi * 16 + row16) * 64 + kgrp * 8 + ks * 32]);
            #pragma unroll
            for (int ni = 0; ni < 4; ++ni)
                bfr[ni] = *reinterpret_cast<const bf16x8*>(
                    &Bs[(wc * 64 + ni * 16 + row16) * 64 + kgrp * 8 + ks * 32]);
            #pragma unroll
            for (int mi = 0; mi < 4; ++mi)
                #pragma unroll
                for (int ni = 0; ni < 4; ++ni)
                    acc[mi][ni] = __builtin_amdgcn_mfma_f32_16x16x32_bf16(
                        af[mi], bfr[ni], acc[mi][ni], 0, 0, 0);
        }
    }

    #pragma unroll
    for (int mi = 0; mi < 4; ++mi) {
        #pragma unroll
        for (int ni = 0; ni < 4; ++ni) {
            #pragma unroll
            for (int r = 0; r < 4; ++r) {
                const int row = bm + wr * 64 + mi * 16 + kgrp * 4 + r;
                const int col = bn + wc * 64 + ni * 16 + row16;
                const float val = acc[mi][ni][r];
                if (mode == 0) {
                    const int which = col >> 10, c = col & 1023;
                    const int n = c >> 6, dh = c & 63;
                    const int i = row >> 1, b = row & 1;
                    const size_t idx = (((size_t)(b * NH + n) * L) + i) * DH + dh;
                    if (which == 0) {
                        const float v0 = val + b0[c];
                        o0[idx] = (__bf16)(v0 + rwbf[c]);
                        o1[idx] = (__bf16)(v0 + rrbf[c]);
                    } else if (which == 1) {
                        o2[idx] = (__bf16)(val + b1[c]);
                    } else {
                        o3[idx] = (__bf16)(val + b2[c]);
                    }
                } else if (mode == 1) {
                    const int n = col >> 6, dh = col & 63;
                    o4[((size_t)n * L + row) * DH + dh] = (__bf16)(val + b3[col]);
                } else {
                    of[(size_t)row * DM + col] = val + b0[col];
                }
            }
        }
    }
}

// ---------------------------------------------------------------------------
// Flash-decoding attention partials: staged K/V^T tiles, double-buffered LDS,
// ONE barrier per tile, async-stage split (loads issued before compute,
// LDS writes after). rk direct from global. Fixed m=0 -> partials add.
// ---------------------------------------------------------------------------
__global__ __launch_bounds__(256, 3)
void attn_partial(const __bf16* __restrict__ qwg, const __bf16* __restrict__ qrg,
                  const __bf16* __restrict__ kg,  const __bf16* __restrict__ vTg,
                  const __bf16* __restrict__ rkg, float* __restrict__ P)
{
    __shared__ __bf16 kt [2][64][72];
    __shared__ __bf16 vtT[2][64][72];  // V^T tile: [d][j]
    __shared__ __bf16 pt [4][16][72];  // per-wave P tile (wave-private)

    // decode chunk id
    int x = blockIdx.x;
    int it, jc;
    if (x < 8)       { it = x;                      jc = 0; }
    else if (x < 24) { int y = x - 8;  it = 8  + (y >> 1); jc = y & 1; }
    else if (x < 48) { int y = x - 24; it = 16 + y / 3;    jc = y - (y / 3) * 3; }
    else             { int y = x - 48; it = 24 + (y >> 2); jc = y & 3; }

    const int t    = threadIdx.x;
    const int w    = t >> 6;
    const int lane = t & 63;
    const int row16 = lane & 15;
    const int kgrp  = lane >> 4;

    const int bh = blockIdx.y;
    const int n  = bh & (NH - 1);
    const int i0 = it * 64;
    const int i0w = i0 + w * 16;
    const int jstart = jc * 512;
    const int jend   = min(jstart + 512, i0 + 64);   // exclusive

    const __bf16* qwb = qwg + (size_t)bh * L * DH;
    const __bf16* qrb = qrg + (size_t)bh * L * DH;
    const __bf16* kb  = kg  + (size_t)bh * L * DH;
    const __bf16* vTb = vTg + (size_t)bh * L * DH;   // [d][j]
    const __bf16* rkb = rkg + (size_t)n  * L * DH;

    bf16x8 qwf[2], qrf[2];
    #pragma unroll
    for (int ks = 0; ks < 2; ++ks) {
        size_t off = (size_t)(i0w + row16) * DH + kgrp * 8 + ks * 32;
        qwf[ks] = *reinterpret_cast<const bf16x8*>(qwb + off);
        qrf[ks] = *reinterpret_cast<const bf16x8*>(qrb + off);
    }

    const int sj = t >> 2;          // staging row (K: j-row, V^T: d-row)
    const int sc = (t & 3) * 16;    // staging col offset

    // ---- prologue: stage first tile into buf 0 ----
    {
        bf16x8 a0 = *reinterpret_cast<const bf16x8*>(kb + (size_t)(jstart + sj) * DH + sc);
        bf16x8 a1 = *reinterpret_cast<const bf16x8*>(kb + (size_t)(jstart + sj) * DH + sc + 8);
        bf16x8 b0v = *reinterpret_cast<const bf16x8*>(vTb + (size_t)sj * L + jstart + sc);
        bf16x8 b1v = *reinterpret_cast<const bf16x8*>(vTb + (size_t)sj * L + jstart + sc + 8);
        *reinterpret_cast<bf16x8*>(&kt[0][sj][sc])      = a0;
        *reinterpret_cast<bf16x8*>(&kt[0][sj][sc + 8])  = a1;
        *reinterpret_cast<bf16x8*>(&vtT[0][sj][sc])     = b0v;
        *reinterpret_cast<bf16x8*>(&vtT[0][sj][sc + 8]) = b1v;
    }
    __syncthreads();

    float l_run[4] = {0.f, 0.f, 0.f, 0.f};
    f32x4 O[4];
    #pragma unroll
    for (int cb = 0; cb < 4; ++cb) O[cb] = (f32x4){0.f, 0.f, 0.f, 0.f};

    int cur = 0;
    for (int j0 = jstart; j0 < jend; j0 += 64) {
        const bool more = (j0 + 64 < jend);

        // ---- issue next-tile global loads (latency hides under compute) ----
        bf16x8 skA, skB, svA, svB;
        if (more) {
            skA = *reinterpret_cast<const bf16x8*>(kb + (size_t)(j0 + 64 + sj) * DH + sc);
            skB = *reinterpret_cast<const bf16x8*>(kb + (size_t)(j0 + 64 + sj) * DH + sc + 8);
            svA = *reinterpret_cast<const bf16x8*>(vTb + (size_t)sj * L + j0 + 64 + sc);
            svB = *reinterpret_cast<const bf16x8*>(vTb + (size_t)sj * L + j0 + 64 + sc + 8);
        }

        // ---- AC = QW · K^T (from LDS buf cur) ----
        f32x4 ac[4];
        #pragma unroll
        for (int cb = 0; cb < 4; ++cb) ac[cb] = (f32x4){0.f, 0.f, 0.f, 0.f};
        #pragma unroll
        for (int ks = 0; ks < 2; ++ks)
            #pragma unroll
            for (int cb = 0; cb < 4; ++cb) {
                bf16x8 kf = *reinterpret_cast<const bf16x8*>(
                    &kt[cur][16 * cb + row16][kgrp * 8 + ks * 32]);
                ac[cb] = __builtin_amdgcn_mfma_f32_16x16x32_bf16(qwf[ks], kf, ac[cb], 0, 0, 0);
            }

        // ---- Dband = QR · RK_band^T (rk direct from global) ----
        f32x4 db[5];
        #pragma unroll
        for (int cb = 0; cb < 5; ++cb) db[cb] = (f32x4){0.f, 0.f, 0.f, 0.f};
        const int pw0 = (L - 1) + j0 - (i0w + 15);
        #pragma unroll
        for (int ks = 0; ks < 2; ++ks)
            #pragma unroll
            for (int cb = 0; cb < 5; ++cb) {
                int p = pw0 + 16 * cb + row16;
                p = p > (L - 1) ? (L - 1) : p;     // clamped rows feed masked cols only
                bf16x8 rf = *reinterpret_cast<const bf16x8*>(
                    rkb + (size_t)p * DH + kgrp * 8 + ks * 32);
                db[cb] = __builtin_amdgcn_mfma_f32_16x16x32_bf16(qrf[ks], rf, db[cb], 0, 0, 0);
            }

        // ---- softmax (fixed m=0) with in-register shift ----
        #pragma unroll
        for (int r = 0; r < 4; ++r) {
            const int ri = kgrp * 4 + r;
            const int i_glob = i0w + ri;
            const int u  = row16 + 15 - ri;        // 0..30
            const int lo = u & 15;
            const int hi = u >> 4;
            const int srclane = (lane & 48) | lo;
            float T[5];
            #pragma unroll
            for (int c2 = 0; c2 < 5; ++c2)
                T[c2] = __shfl(db[c2][r], srclane, 64);
            float rsum = 0.f;
            #pragma unroll
            for (int cb = 0; cb < 4; ++cb) {
                const int jj = 16 * cb + row16;
                float bd = hi ? T[cb + 1] : T[cb];
                float s = SCALE_F * (ac[cb][r] + bd);
                if (j0 + jj > i_glob) s = -INFINITY;
                float p = __expf(s);
                pt[w][ri][jj] = (__bf16)p;
                rsum += p;
            }
            #pragma unroll
            for (int off = 1; off < 16; off <<= 1)
                rsum += __shfl_xor(rsum, off);
            l_run[r] += rsum;
        }

        // ---- O += P · V (A=P wave-private LDS, B=V^T from buf cur) ----
        #pragma unroll
        for (int ks = 0; ks < 2; ++ks) {
            bf16x8 pf = *reinterpret_cast<const bf16x8*>(&pt[w][row16][kgrp * 8 + ks * 32]);
            #pragma unroll
            for (int cb = 0; cb < 4; ++cb) {
                bf16x8 vf = *reinterpret_cast<const bf16x8*>(
                    &vtT[cur][16 * cb + row16][kgrp * 8 + ks * 32]);
                O[cb] = __builtin_amdgcn_mfma_f32_16x16x32_bf16(pf, vf, O[cb], 0, 0, 0);
            }
        }

        // ---- write staged tile to buf^1, single barrier ----
        if (more) {
            *reinterpret_cast<bf16x8*>(&kt[cur ^ 1][sj][sc])      = skA;
            *reinterpret_cast<bf16x8*>(&kt[cur ^ 1][sj][sc + 8])  = skB;
            *reinterpret_cast<bf16x8*>(&vtT[cur ^ 1][sj][sc])     = svA;
            *reinterpret_cast<bf16x8*>(&vtT[cur ^ 1][sj][sc + 8]) = svB;
            __syncthreads();
            cur ^= 1;
        }
    }

    // ---- accumulate partials ----
    float* Pb = P + ((size_t)bh * 32 + it) * PSLOT;
    #pragma unroll
    for (int r = 0; r < 4; ++r) {
        const int row = w * 16 + kgrp * 4 + r;
        #pragma unroll
        for (int cb = 0; cb < 4; ++cb)
            atomicAdd(&Pb[row * 64 + 16 * cb + row16], O[cb][r]);
        if (row16 == 0)
            atomicAdd(&Pb[4096 + row], l_run[r]);
    }
}

// ---------------------------------------------------------------------------
// Combine partials: av = O_sum / l_sum, bf16, attn_vec layout.
// ---------------------------------------------------------------------------
__global__ __launch_bounds__(256)
void attn_reduce(const float* __restrict__ P, __bf16* __restrict__ av)
{
    const int bh = blockIdx.y;
    const int it = blockIdx.x;
    const int n = bh & (NH - 1), b = bh >> 4;
    const float* Pb = P + ((size_t)bh * 32 + it) * PSLOT;
    const int t = threadIdx.x;
    const int row = t >> 2;
    const int c0 = (t & 3) * 16;
    const float inv = 1.0f / Pb[4096 + row];
    const int i_glob = it * 64 + row;
    __bf16* dst = av + (size_t)(i_glob * BSZ + b) * (NH * DH) + n * DH + c0;
    #pragma unroll
    for (int v4 = 0; v4 < 4; ++v4) {
        float4 o = *reinterpret_cast<const float4*>(&Pb[row * 64 + c0 + v4 * 4]);
        bf16x4 ov = { (__bf16)(o.x * inv), (__bf16)(o.y * inv),
                      (__bf16)(o.z * inv), (__bf16)(o.w * inv) };
        *reinterpret_cast<bf16x4*>(dst + v4 * 4) = ov;
    }
}

// ---------------------------------------------------------------------------
// Fused residual + LayerNorm
// ---------------------------------------------------------------------------
__global__ __launch_bounds__(256)
void ln_fused(const float* __restrict__ w, const float* __restrict__ ao,
              const float* __restrict__ g, const float* __restrict__ bb,
              float* __restrict__ out)
{
    const int row = blockIdx.x;
    const float* wr = w  + (size_t)row * DM;
    const float* ar = ao + (size_t)row * DM;
    const int t = threadIdx.x;
    float x[4];
    float s = 0.f;
    #pragma unroll
    for (int j = 0; j < 4; ++j) {
        int c = t + j * 256;
        x[j] = wr[c] + ar[c];
        s += x[j];
    }
    __shared__ float red[4];
    #pragma unroll
    for (int off = 1; off < 64; off <<= 1) s += __shfl_xor(s, off);
    int wid = t >> 6, lane = t & 63;
    if (lane == 0) red[wid] = s;
    __syncthreads();
    float mu = (red[0] + red[1] + red[2] + red[3]) * (1.0f / DM);
    float ss = 0.f;
    #pragma unroll
    for (int j = 0; j < 4; ++j) { float d = x[j] - mu; ss += d * d; }
    #pragma unroll
    for (int off = 1; off < 64; off <<= 1) ss += __shfl_xor(ss, off);
    __syncthreads();
    if (lane == 0) red[wid] = ss;
    __syncthreads();
    float var = (red[0] + red[1] + red[2] + red[3]) * (1.0f / DM);
    float rstd = rsqrtf(var + 1e-5f);
    #pragma unroll
    for (int j = 0; j < 4; ++j) {
        int c = t + j * 256;
        out[(size_t)row * DM + c] = (x[j] - mu) * rstd * g[c] + bb[c];
    }
}

extern "C" void kernel_launch(void* const* d_in, const int* in_sizes, int n_in,
                              void* d_out, int out_size, void* d_ws, size_t ws_size,
                              hipStream_t stream)
{
    (void)in_sizes; (void)n_in; (void)out_size; (void)ws_size;
    const float* w   = (const float*)d_in[0];
    const float* r   = (const float*)d_in[1];
    const float* rwb = (const float*)d_in[2];
    const float* rrb = (const float*)d_in[3];
    const float* Wq  = (const float*)d_in[4];
    const float* bq  = (const float*)d_in[5];
    const float* Wk  = (const float*)d_in[6];
    const float* bk  = (const float*)d_in[7];
    const float* Wv  = (const float*)d_in[8];
    const float* bv  = (const float*)d_in[9];
    const float* Wr  = (const float*)d_in[10];
    const float* br  = (const float*)d_in[11];
    const float* Wo  = (const float*)d_in[12];
    const float* bo  = (const float*)d_in[13];
    const float* lng = (const float*)d_in[14];
    const float* lnb = (const float*)d_in[15];
    float* out = (float*)d_out;

    const size_t NQ = (size_t)BSZ * NH * L * DH;   // 4.19M
    const size_t PN = (size_t)BSZ * NH * 32 * PSLOT;  // 4.26M f32 partial buffer
    char* wsb = (char*)d_ws;
    __bf16* w_bf    = (__bf16*)wsb;  wsb += (size_t)2 * L * DM * 2;
    __bf16* r_bf    = (__bf16*)wsb;  wsb += (size_t)L * DM * 2;
    __bf16* wqkv_t  = (__bf16*)wsb;  wsb += (size_t)3 * DM * DM * 2;
    __bf16* wr_t    = (__bf16*)wsb;  wsb += (size_t)DM * DM * 2;
    __bf16* wo_t    = (__bf16*)wsb;  wsb += (size_t)DM * DM * 2;
    __bf16* qw_ws   = (__bf16*)wsb;  wsb += NQ * 2;
    __bf16* qr_ws   = (__bf16*)wsb;  wsb += NQ * 2;
    __bf16* k_ws    = (__bf16*)wsb;  wsb += NQ * 2;
    __bf16* v_ws    = (__bf16*)wsb;  wsb += NQ * 2;
    __bf16* vT_ws   = (__bf16*)wsb;  wsb += NQ * 2;
    __bf16* rk_ws   = (__bf16*)wsb;  wsb += (size_t)NH * L * DH * 2;
    __bf16* av_ws   = (__bf16*)wsb;  wsb += NQ * 2;
    float*  P_ws    = (float*)wsb;   // PN floats; ao_ws ALIASES this region:
    float*  ao_ws   = P_ws;          // P consumed by attn_reduce before o-proj writes ao

    dim3 blk(256);
    // zero partial accumulators (capture-legal async memset)
    hipMemsetAsync(P_ws, 0, PN * sizeof(float), stream);

    cast2_f32_bf16<<<dim3(1536), blk, 0, stream>>>(
        w, (2 * L * DM) / 4, r, (L * DM) / 4, w_bf, r_bf);
    transpose_w5<<<dim3(32, 32, 5), blk, 0, stream>>>(
        Wq, Wk, Wv, Wr, Wo,
        wqkv_t, wqkv_t + (size_t)DM * DM, wqkv_t + (size_t)2 * DM * DM, wr_t, wo_t);

    // fused QKV (768 blocks) + RK (128 blocks -> o4/b3)
    gemm_bf16<<<dim3(896), blk, 0, stream>>>(w_bf, r_bf, wqkv_t, wr_t, 0,
        qw_ws, qr_ws, k_ws, v_ws, rk_ws, bq, bk, bv, br, rwb, rrb, nullptr);

    // V transpose for LDS-staged PV B-operand
    transpose_v<<<dim3(L / 32, DH / 32, BSZ * NH), blk, 0, stream>>>(v_ws, vT_ws);

    // flash-decoding attention: dbuf-staged partials + reduce
    attn_partial<<<dim3(80, BSZ * NH), blk, 0, stream>>>(
        qw_ws, qr_ws, k_ws, vT_ws, rk_ws, P_ws);
    attn_reduce<<<dim3(32, BSZ * NH), blk, 0, stream>>>(P_ws, av_ws);

    // output projection -> fp32 (overwrites P region, already consumed)
    gemm_bf16<<<dim3(32, 8), blk, 0, stream>>>(av_ws, nullptr, wo_t, nullptr, 1,
        nullptr, nullptr, nullptr, nullptr, nullptr, bo, nullptr, nullptr, nullptr,
        nullptr, nullptr, ao_ws);

    ln_fused<<<dim3(L * BSZ), blk, 0, stream>>>(w, ao_ws, lng, lnb, out);
}